// Round 4
// baseline (224.429 us; speedup 1.0000x reference)
//
#include <hip/hip_runtime.h>
#include <hip/hip_bf16.h>

typedef __attribute__((ext_vector_type(8))) short short8;
typedef __attribute__((ext_vector_type(4))) float f32x4;

#define LDW 40   // padded LDS row length in ushorts (80 B)

__device__ __forceinline__ unsigned short f2bf(float f) {
  __hip_bfloat16 h = __float2bfloat16(f);   // RNE; compiler can fuse pairs into v_cvt_pk_bf16_f32
  return *(unsigned short*)&h;
}
__device__ __forceinline__ float bf2f(unsigned h) {
  return __uint_as_float(h << 16);
}
__device__ __forceinline__ unsigned pk2(float a, float b) {
  return (unsigned)f2bf(a) | ((unsigned)f2bf(b) << 16);
}
__device__ __forceinline__ unsigned long long pack4(float a, float b, float c, float d) {
  return (unsigned long long)pk2(a, b) | ((unsigned long long)pk2(c, d) << 32);
}

// ---------------- zero the S0 + bn_acc accumulators (replaces hipMemsetAsync)
__global__ void zero_acc(float* p) { p[threadIdx.x] = 0.f; }

// ---------------- Phase 1: conv as bf16 MFMA GEMM, y bf16 [b][d][n], BN partials via atomicAdd
__global__ __launch_bounds__(256) void conv_mfma(const float* __restrict__ x,
    const float* __restrict__ w, const float* __restrict__ bias,
    unsigned short* __restrict__ y, float* __restrict__ bn_acc) {
  const int b = blockIdx.y;
  const int n0 = blockIdx.x * 128;
  const int tid = threadIdx.x;
  const int lane = tid & 63, wv = tid >> 6;
  const int li = lane & 15, q = lane >> 4;
  __shared__ unsigned short Wl[128 * LDW];   // W[d][c-chunk] bf16
  __shared__ unsigned short Xl[128 * LDW];   // X^T[n][c-chunk] bf16
  f32x4 acc[2][8];
#pragma unroll
  for (int m = 0; m < 2; ++m)
#pragma unroll
    for (int r = 0; r < 8; ++r) acc[m][r] = (f32x4){0.f, 0.f, 0.f, 0.f};
  const float* xb = x + (size_t)b * (512 * 4096) + n0;
  const int xn = tid & 127, xch = tid >> 7;
  for (int c0 = 0; c0 < 512; c0 += 32) {
#pragma unroll
    for (int i = 0; i < 4; ++i) {
      int idx = tid + i * 256;
      int d = idx >> 3, c4 = (idx & 7) * 4;
      float4 v = *(const float4*)(w + (size_t)d * 512 + c0 + c4);
      *(unsigned long long*)&Wl[d * LDW + c4] = pack4(v.x, v.y, v.z, v.w);
    }
#pragma unroll
    for (int p = 0; p < 4; ++p) {
      int c = (xch + p * 2) * 4;
      const float* xp = xb + (size_t)(c0 + c) * 4096 + xn;
      float v0 = xp[0];
      float v1 = xp[4096];
      float v2 = xp[2 * 4096];
      float v3 = xp[3 * 4096];
      *(unsigned long long*)&Xl[xn * LDW + c] = pack4(v0, v1, v2, v3);
    }
    __syncthreads();
    short8 af[2], bfr[8];
#pragma unroll
    for (int m = 0; m < 2; ++m)
      af[m] = *(const short8*)&Xl[(32 * wv + 16 * m + li) * LDW + q * 8];
#pragma unroll
    for (int r = 0; r < 8; ++r)
      bfr[r] = *(const short8*)&Wl[(16 * r + li) * LDW + q * 8];
#pragma unroll
    for (int m = 0; m < 2; ++m)
#pragma unroll
      for (int r = 0; r < 8; ++r)
        acc[m][r] = __builtin_amdgcn_mfma_f32_16x16x32_bf16(af[m], bfr[r], acc[m][r], 0, 0, 0);
    __syncthreads();
  }
  float s1[8], s2[8];
#pragma unroll
  for (int r = 0; r < 8; ++r) { s1[r] = 0.f; s2[r] = 0.f; }
#pragma unroll
  for (int r = 0; r < 8; ++r) {
    int d = 16 * r + li;
    float bb = bias[d];
#pragma unroll
    for (int m = 0; m < 2; ++m) {
      int nl = 32 * wv + 16 * m + 4 * q;
      float v0 = acc[m][r][0] + bb, v1 = acc[m][r][1] + bb;
      float v2 = acc[m][r][2] + bb, v3 = acc[m][r][3] + bb;
      s1[r] += v0 + v1 + v2 + v3;
      s2[r] += v0 * v0 + v1 * v1 + v2 * v2 + v3 * v3;
      *(unsigned long long*)(y + ((size_t)(b * 128 + d)) * 4096 + n0 + nl) =
          pack4(v0, v1, v2, v3);
    }
  }
#pragma unroll
  for (int r = 0; r < 8; ++r) {
    s1[r] += __shfl_xor(s1[r], 16); s1[r] += __shfl_xor(s1[r], 32);
    s2[r] += __shfl_xor(s2[r], 16); s2[r] += __shfl_xor(s2[r], 32);
  }
  float* red = (float*)Wl;
  if (lane < 16) {
#pragma unroll
    for (int r = 0; r < 8; ++r) {
      red[0 * 512 + wv * 128 + r * 16 + li] = s1[r];
      red[1 * 512 + wv * 128 + r * 16 + li] = s2[r];
    }
  }
  __syncthreads();
  {
    int s = tid >> 7, d = tid & 127;
    float v = red[s * 512 + d] + red[s * 512 + 128 + d]
            + red[s * 512 + 256 + d] + red[s * 512 + 384 + d];
    atomicAdd(&bn_acc[s * 128 + d], v);
  }
}

// ---------------- Phase 3: softmax assignment (1 token/thread)
__global__ __launch_bounds__(256) void assign_softmax(const unsigned short* __restrict__ y,
    const float* __restrict__ bn_acc, const float* __restrict__ bn_g,
    const float* __restrict__ bn_b, const float* __restrict__ cw,
    const float* __restrict__ scale, float* __restrict__ A, float* __restrict__ S0) {
  const int b = blockIdx.y;
  const int tid = threadIdx.x;
  const int n = blockIdx.x * 256 + tid;
  __shared__ float cws[16][128];
  __shared__ float c2s[16], scs[128], shs[128], sscale[16];
  for (int i = tid; i < 2048; i += 256) cws[i >> 7][i & 127] = cw[i];
  if (tid < 128) {
    float mu = bn_acc[tid] * (1.f / 65536.f);
    float var = bn_acc[128 + tid] * (1.f / 65536.f) - mu * mu;
    float sc = rsqrtf(var + 1e-5f) * bn_g[tid];
    scs[tid] = sc;
    shs[tid] = bn_b[tid] - mu * sc;
  }
  if (tid < 16) sscale[tid] = scale[tid];
  __syncthreads();
  if (tid < 16) {
    float s = 0.f;
#pragma unroll
    for (int d = 0; d < 128; ++d) s += cws[tid][d] * cws[tid][d];
    c2s[tid] = s;
  }
  __syncthreads();
  float dot[16];
#pragma unroll
  for (int k = 0; k < 16; ++k) dot[k] = 0.f;
  float x2 = 0.f;
  const unsigned short* yb = y + (size_t)b * 524288 + n;
  for (int d4 = 0; d4 < 128; d4 += 4) {
    float xv[4];
#pragma unroll
    for (int j = 0; j < 4; ++j) {
      unsigned h = yb[(size_t)(d4 + j) * 4096];
      float v = fmaxf(fmaf(bf2f(h), scs[d4 + j], shs[d4 + j]), 0.f);
      xv[j] = v;
      x2 = fmaf(v, v, x2);
    }
#pragma unroll
    for (int k = 0; k < 16; ++k) {
      float4 cv = *(const float4*)&cws[k][d4];
      dot[k] += xv[0] * cv.x + xv[1] * cv.y + xv[2] * cv.z + xv[3] * cv.w;
    }
  }
  float p[16];
  {
    float m = -1e30f, sl[16];
#pragma unroll
    for (int k = 0; k < 16; ++k) {
      sl[k] = sscale[k] * (x2 + c2s[k] - 2.f * dot[k]);
      m = fmaxf(m, sl[k]);
    }
    float s = 0.f;
#pragma unroll
    for (int k = 0; k < 16; ++k) { p[k] = __expf(sl[k] - m); s += p[k]; }
    float inv = 1.f / s;
#pragma unroll
    for (int k = 0; k < 16; ++k) p[k] *= inv;
  }
  float4* Ap = (float4*)(A + ((size_t)b * 4096 + n) * 16);
  Ap[0] = make_float4(p[0], p[1], p[2], p[3]);
  Ap[1] = make_float4(p[4], p[5], p[6], p[7]);
  Ap[2] = make_float4(p[8], p[9], p[10], p[11]);
  Ap[3] = make_float4(p[12], p[13], p[14], p[15]);
  const int lane = tid & 63;
#pragma unroll
  for (int k = 0; k < 16; ++k) {
    float v = p[k];
#pragma unroll
    for (int off = 32; off; off >>= 1) v += __shfl_xor(v, off);
    if (lane == 0) atomicAdd(&S0[b * 16 + k], v);
  }
}

// ---------------- Phase 4: E[b,k,d] = sum_n A[b,n,k]*X[b,n,d] - S0[b,k]*cw[k,d]
__global__ __launch_bounds__(256) void aggregate(const unsigned short* __restrict__ y,
    const float* __restrict__ bn_acc, const float* __restrict__ bn_g,
    const float* __restrict__ bn_b, const float* __restrict__ A,
    const float* __restrict__ S0, const float* __restrict__ cw,
    float* __restrict__ e_raw) {
  const int b = blockIdx.y;
  const int d0 = blockIdx.x * 4;
  const int tid = threadIdx.x;
  __shared__ float scsh[8];
  if (tid < 4) {
    int d = d0 + tid;
    float mu = bn_acc[d] * (1.f / 65536.f);
    float var = bn_acc[128 + d] * (1.f / 65536.f) - mu * mu;
    float sc = rsqrtf(var + 1e-5f) * bn_g[d];
    scsh[tid] = sc;
    scsh[4 + tid] = bn_b[d] - mu * sc;
  }
  __syncthreads();
  float sc[4], sh[4];
#pragma unroll
  for (int i = 0; i < 4; ++i) { sc[i] = scsh[i]; sh[i] = scsh[4 + i]; }
  float acc[4][16];
#pragma unroll
  for (int i = 0; i < 4; ++i)
#pragma unroll
    for (int k = 0; k < 16; ++k) acc[i][k] = 0.f;
  const unsigned short* yb = y + ((size_t)b * 128 + d0) * 4096;
  const float* Ab = A + (size_t)b * 65536;
  for (int it = 0; it < 8; ++it) {
    int n = (it * 256 + tid) * 2;
    float xv0[4], xv1[4];
#pragma unroll
    for (int i = 0; i < 4; ++i) {
      unsigned pr = *(const unsigned*)(yb + (size_t)i * 4096 + n);
      xv0[i] = fmaxf(fmaf(bf2f(pr & 0xFFFFu), sc[i], sh[i]), 0.f);
      xv1[i] = fmaxf(fmaf(bf2f(pr >> 16), sc[i], sh[i]), 0.f);
    }
    const float4* ap = (const float4*)(Ab + (size_t)n * 16);
    float4 a0 = ap[0], a1 = ap[1], a2 = ap[2], a3 = ap[3];
    float4 b0 = ap[4], b1 = ap[5], b2 = ap[6], b3 = ap[7];
    float av0[16] = {a0.x, a0.y, a0.z, a0.w, a1.x, a1.y, a1.z, a1.w,
                     a2.x, a2.y, a2.z, a2.w, a3.x, a3.y, a3.z, a3.w};
    float av1[16] = {b0.x, b0.y, b0.z, b0.w, b1.x, b1.y, b1.z, b1.w,
                     b2.x, b2.y, b2.z, b2.w, b3.x, b3.y, b3.z, b3.w};
#pragma unroll
    for (int i = 0; i < 4; ++i)
#pragma unroll
      for (int k = 0; k < 16; ++k)
        acc[i][k] += av0[k] * xv0[i] + av1[k] * xv1[i];
  }
  const int lane = tid & 63, wid = tid >> 6;
  __shared__ float red[4][4][16];
#pragma unroll
  for (int i = 0; i < 4; ++i)
#pragma unroll
    for (int k = 0; k < 16; ++k) {
      float v = acc[i][k];
#pragma unroll
      for (int off = 32; off; off >>= 1) v += __shfl_xor(v, off);
      if (lane == 0) red[wid][i][k] = v;
    }
  __syncthreads();
  if (tid < 64) {
    int i = tid >> 4, k = tid & 15;
    float v = red[0][i][k] + red[1][i][k] + red[2][i][k] + red[3][i][k];
    int d = d0 + i;
    e_raw[(size_t)b * 2048 + k * 128 + d] = v - S0[b * 16 + k] * cw[k * 128 + d];
  }
}

// ---------------- Phase 5: gate = sigmoid((lin_w·e)/max(||e||,eps) + lin_b)
__global__ __launch_bounds__(256) void gate_kernel(const float* __restrict__ e_raw,
    const float* __restrict__ lin_w, const float* __restrict__ lin_b,
    float* __restrict__ gate) {
  const int b = blockIdx.y;
  const int c0 = blockIdx.x * 64;
  const int tid = threadIdx.x;
  __shared__ float es[2048];
  __shared__ float sred[256];
  __shared__ float s_inv;
  const float* eb = e_raw + (size_t)b * 2048;
  float ss = 0.f;
  for (int i = tid; i < 512; i += 256) {
    float4 v = ((const float4*)eb)[i];
    *(float4*)&es[i * 4] = v;
    ss += v.x * v.x + v.y * v.y + v.z * v.z + v.w * v.w;
  }
  sred[tid] = ss;
  __syncthreads();
  for (int off = 128; off; off >>= 1) {
    if (tid < off) sred[tid] += sred[tid + off];
    __syncthreads();
  }
  if (tid == 0) s_inv = 1.f / fmaxf(sqrtf(sred[0]), 1e-12f);
  __syncthreads();
  const int lane = tid & 63, wid = tid >> 6;
  for (int i = 0; i < 16; ++i) {
    int c = c0 + wid * 16 + i;
    const float* wr = lin_w + (size_t)c * 2048;
    float dotv = 0.f;
#pragma unroll
    for (int j = 0; j < 8; ++j) {
      int idx = j * 64 + lane;
      float4 wv = ((const float4*)wr)[idx];
      const float* ep = &es[idx * 4];
      dotv += wv.x * ep[0] + wv.y * ep[1] + wv.z * ep[2] + wv.w * ep[3];
    }
#pragma unroll
    for (int off = 32; off; off >>= 1) dotv += __shfl_xor(dotv, off);
    if (lane == 0) {
      float z = dotv * s_inv + lin_b[c];
      gate[b * 512 + c] = 1.f / (1.f + __expf(-z));
    }
  }
}

// ---------------- Phase 6: out = x * gate[b,c]
__global__ __launch_bounds__(256) void scale_kernel(const float* __restrict__ x,
    const float* __restrict__ gate, float* __restrict__ out, long n4) {
  long i = (long)blockIdx.x * blockDim.x + threadIdx.x;
  long stride = (long)gridDim.x * blockDim.x;
  for (; i < n4; i += stride) {
    float4 v = ((const float4*)x)[i];
    int c = (int)((i >> 10) & 511);
    int b = (int)(i >> 19);
    float g = gate[(b << 9) | c];
    v.x *= g; v.y *= g; v.z *= g; v.w *= g;
    ((float4*)out)[i] = v;
  }
}

extern "C" void kernel_launch(void* const* d_in, const int* in_sizes, int n_in,
                              void* d_out, int out_size, void* d_ws, size_t ws_size,
                              hipStream_t stream) {
  const float* x      = (const float*)d_in[0];
  const float* conv_w = (const float*)d_in[1];
  const float* conv_b = (const float*)d_in[2];
  const float* bn_g   = (const float*)d_in[3];
  const float* bn_b   = (const float*)d_in[4];
  const float* cw     = (const float*)d_in[5];
  const float* scale  = (const float*)d_in[6];
  const float* lin_w  = (const float*)d_in[7];
  const float* lin_b  = (const float*)d_in[8];
  float* out = (float*)d_out;
  float* ws  = (float*)d_ws;

  unsigned short* y = (unsigned short*)ws;      // [0, 4194304) floats
  float* A      = ws + 4194304;                 // 1,048,576
  float* S0     = ws + 5242880;                 // 256
  float* bn_acc = ws + 5243136;                 // 256
  float* e_raw  = ws + 5243392;                 // 32,768
  float* gate   = ws + 5276160;                 // 8,192

  zero_acc<<<1, 512, 0, stream>>>(S0);          // zeros S0 + bn_acc (contiguous)
  conv_mfma<<<dim3(32, 16), 256, 0, stream>>>(x, conv_w, conv_b, y, bn_acc);
  assign_softmax<<<dim3(16, 16), 256, 0, stream>>>(y, bn_acc, bn_g, bn_b, cw, scale, A, S0);
  aggregate<<<dim3(32, 16), 256, 0, stream>>>(y, bn_acc, bn_g, bn_b, A, S0, cw, e_raw);
  gate_kernel<<<dim3(8, 16), 256, 0, stream>>>(e_raw, lin_w, lin_b, gate);
  scale_kernel<<<4096, 256, 0, stream>>>(x, gate, out, 8388608L);
}

// Round 5
// 208.185 us; speedup vs baseline: 1.0780x; 1.0780x over previous
//
#include <hip/hip_runtime.h>
#include <hip/hip_bf16.h>

typedef __attribute__((ext_vector_type(8))) short short8;
typedef __attribute__((ext_vector_type(4))) float f32x4;

#define LDW 40   // padded LDS row length in ushorts (80 B)

__device__ __forceinline__ unsigned short f2bf(float f) {
  __hip_bfloat16 h = __float2bfloat16(f);
  return *(unsigned short*)&h;
}
__device__ __forceinline__ float bf2f(unsigned h) {
  return __uint_as_float(h << 16);
}
__device__ __forceinline__ unsigned pk2(float a, float b) {
  return (unsigned)f2bf(a) | ((unsigned)f2bf(b) << 16);
}
__device__ __forceinline__ unsigned long long pack4(float a, float b, float c, float d) {
  return (unsigned long long)pk2(a, b) | ((unsigned long long)pk2(c, d) << 32);
}

// ---------------- prep: convert conv_w to bf16 [d][c] AND zero S0+bn_acc
__global__ __launch_bounds__(256) void prep(const float* __restrict__ w,
    unsigned short* __restrict__ w_bf, float* __restrict__ S0) {
  int i = (blockIdx.x * 256 + threadIdx.x) * 4;
  float4 v = *(const float4*)(w + i);
  *(unsigned long long*)(w_bf + i) = pack4(v.x, v.y, v.z, v.w);
  if (blockIdx.x == 0) {
    S0[threadIdx.x] = 0.f;
    S0[256 + threadIdx.x] = 0.f;
  }
}

// ---------------- Phase 1: conv as bf16 MFMA GEMM, y bf16 [b][d][n], BN partials via atomicAdd
__global__ __launch_bounds__(256) void conv_mfma(const float* __restrict__ x,
    const unsigned short* __restrict__ w_bf, const float* __restrict__ bias,
    unsigned short* __restrict__ y, float* __restrict__ bn_acc) {
  const int b = blockIdx.y;
  const int n0 = blockIdx.x * 128;
  const int tid = threadIdx.x;
  const int lane = tid & 63, wv = tid >> 6;
  const int li = lane & 15, q = lane >> 4;
  __shared__ unsigned short Wl[128 * LDW];   // W[d][c-chunk] bf16
  __shared__ unsigned short Xl[128 * LDW];   // X^T[n][c-chunk] bf16
  f32x4 acc[2][8];
#pragma unroll
  for (int m = 0; m < 2; ++m)
#pragma unroll
    for (int r = 0; r < 8; ++r) acc[m][r] = (f32x4){0.f, 0.f, 0.f, 0.f};
  const float* xb = x + (size_t)b * (512 * 4096) + n0;
  const int nq = tid & 31, cg = tid >> 5;    // nq: n-quad, cg: c-group of 4
  for (int c0 = 0; c0 < 512; c0 += 32) {
    // stage W[0..128)[c0..c0+32) bf16 copy: 512 short8 chunks / 256 threads
#pragma unroll
    for (int i = 0; i < 2; ++i) {
      int idx = tid + i * 256;
      int d = idx >> 2, h = idx & 3;
      *(short8*)&Wl[d * LDW + h * 8] = *(const short8*)(w_bf + (size_t)d * 512 + c0 + h * 8);
    }
    // stage X^T[n][c]: 4 float4 loads (4 n x 4 c), pack -> 4 b64 LDS writes
    {
      const float* xp = xb + (size_t)(c0 + cg * 4) * 4096 + nq * 4;
      float4 v0 = *(const float4*)(xp);
      float4 v1 = *(const float4*)(xp + 4096);
      float4 v2 = *(const float4*)(xp + 2 * 4096);
      float4 v3 = *(const float4*)(xp + 3 * 4096);
      const float* a0 = (const float*)&v0;
      const float* a1 = (const float*)&v1;
      const float* a2 = (const float*)&v2;
      const float* a3 = (const float*)&v3;
#pragma unroll
      for (int j = 0; j < 4; ++j) {
        *(unsigned long long*)&Xl[(nq * 4 + j) * LDW + cg * 4] =
            pack4(a0[j], a1[j], a2[j], a3[j]);
      }
    }
    __syncthreads();
    short8 af[2], bfr[8];
#pragma unroll
    for (int m = 0; m < 2; ++m)
      af[m] = *(const short8*)&Xl[(32 * wv + 16 * m + li) * LDW + q * 8];
#pragma unroll
    for (int r = 0; r < 8; ++r)
      bfr[r] = *(const short8*)&Wl[(16 * r + li) * LDW + q * 8];
#pragma unroll
    for (int m = 0; m < 2; ++m)
#pragma unroll
      for (int r = 0; r < 8; ++r)
        acc[m][r] = __builtin_amdgcn_mfma_f32_16x16x32_bf16(af[m], bfr[r], acc[m][r], 0, 0, 0);
    __syncthreads();
  }
  float s1[8], s2[8];
#pragma unroll
  for (int r = 0; r < 8; ++r) { s1[r] = 0.f; s2[r] = 0.f; }
#pragma unroll
  for (int r = 0; r < 8; ++r) {
    int d = 16 * r + li;
    float bb = bias[d];
#pragma unroll
    for (int m = 0; m < 2; ++m) {
      int nl = 32 * wv + 16 * m + 4 * q;
      float v0 = acc[m][r][0] + bb, v1 = acc[m][r][1] + bb;
      float v2 = acc[m][r][2] + bb, v3 = acc[m][r][3] + bb;
      s1[r] += v0 + v1 + v2 + v3;
      s2[r] += v0 * v0 + v1 * v1 + v2 * v2 + v3 * v3;
      *(unsigned long long*)(y + ((size_t)(b * 128 + d)) * 4096 + n0 + nl) =
          pack4(v0, v1, v2, v3);
    }
  }
#pragma unroll
  for (int r = 0; r < 8; ++r) {
    s1[r] += __shfl_xor(s1[r], 16); s1[r] += __shfl_xor(s1[r], 32);
    s2[r] += __shfl_xor(s2[r], 16); s2[r] += __shfl_xor(s2[r], 32);
  }
  float* red = (float*)Wl;
  if (lane < 16) {
#pragma unroll
    for (int r = 0; r < 8; ++r) {
      red[0 * 512 + wv * 128 + r * 16 + li] = s1[r];
      red[1 * 512 + wv * 128 + r * 16 + li] = s2[r];
    }
  }
  __syncthreads();
  {
    int s = tid >> 7, d = tid & 127;
    float v = red[s * 512 + d] + red[s * 512 + 128 + d]
            + red[s * 512 + 256 + d] + red[s * 512 + 384 + d];
    atomicAdd(&bn_acc[s * 128 + d], v);
  }
}

// ---------------- Phase 3: softmax assignment (2 tokens/thread, dword y loads)
__global__ __launch_bounds__(256) void assign_softmax(const unsigned short* __restrict__ y,
    const float* __restrict__ bn_acc, const float* __restrict__ bn_g,
    const float* __restrict__ bn_b, const float* __restrict__ cw,
    const float* __restrict__ scale, float* __restrict__ A, float* __restrict__ S0) {
  const int b = blockIdx.y;
  const int tid = threadIdx.x;
  const int n = (blockIdx.x * 256 + tid) * 2;
  __shared__ float cws[16][128];
  __shared__ float c2s[16], scs[128], shs[128], sscale[16];
  for (int i = tid; i < 2048; i += 256) cws[i >> 7][i & 127] = cw[i];
  if (tid < 128) {
    float mu = bn_acc[tid] * (1.f / 65536.f);
    float var = bn_acc[128 + tid] * (1.f / 65536.f) - mu * mu;
    float sc = rsqrtf(var + 1e-5f) * bn_g[tid];
    scs[tid] = sc;
    shs[tid] = bn_b[tid] - mu * sc;
  }
  if (tid < 16) sscale[tid] = scale[tid];
  __syncthreads();
  if (tid < 16) {
    float s = 0.f;
#pragma unroll
    for (int d = 0; d < 128; ++d) s += cws[tid][d] * cws[tid][d];
    c2s[tid] = s;
  }
  __syncthreads();
  float dot0[16], dot1[16];
#pragma unroll
  for (int k = 0; k < 16; ++k) { dot0[k] = 0.f; dot1[k] = 0.f; }
  float x20 = 0.f, x21 = 0.f;
  const unsigned short* yb = y + (size_t)b * 524288 + n;
  for (int d4 = 0; d4 < 128; d4 += 4) {
    float xv0[4], xv1[4];
#pragma unroll
    for (int j = 0; j < 4; ++j) {
      unsigned pr = *(const unsigned*)(yb + (size_t)(d4 + j) * 4096);
      float sc = scs[d4 + j], sh = shs[d4 + j];
      float a0 = fmaxf(fmaf(bf2f(pr & 0xFFFFu), sc, sh), 0.f);
      float a1 = fmaxf(fmaf(bf2f(pr >> 16), sc, sh), 0.f);
      xv0[j] = a0; xv1[j] = a1;
      x20 = fmaf(a0, a0, x20); x21 = fmaf(a1, a1, x21);
    }
#pragma unroll
    for (int k = 0; k < 16; ++k) {
      float4 cv = *(const float4*)&cws[k][d4];
      dot0[k] += xv0[0] * cv.x + xv0[1] * cv.y + xv0[2] * cv.z + xv0[3] * cv.w;
      dot1[k] += xv1[0] * cv.x + xv1[1] * cv.y + xv1[2] * cv.z + xv1[3] * cv.w;
    }
  }
  float p0[16], p1[16];
  {
    float m0 = -1e30f, m1 = -1e30f;
    float sl0[16], sl1[16];
#pragma unroll
    for (int k = 0; k < 16; ++k) {
      sl0[k] = sscale[k] * (x20 + c2s[k] - 2.f * dot0[k]);
      sl1[k] = sscale[k] * (x21 + c2s[k] - 2.f * dot1[k]);
      m0 = fmaxf(m0, sl0[k]); m1 = fmaxf(m1, sl1[k]);
    }
    float s0 = 0.f, s1 = 0.f;
#pragma unroll
    for (int k = 0; k < 16; ++k) {
      p0[k] = __expf(sl0[k] - m0); s0 += p0[k];
      p1[k] = __expf(sl1[k] - m1); s1 += p1[k];
    }
    float i0 = 1.f / s0, i1 = 1.f / s1;
#pragma unroll
    for (int k = 0; k < 16; ++k) { p0[k] *= i0; p1[k] *= i1; }
  }
  float4* Ap = (float4*)(A + ((size_t)b * 4096 + n) * 16);
  Ap[0] = make_float4(p0[0], p0[1], p0[2], p0[3]);
  Ap[1] = make_float4(p0[4], p0[5], p0[6], p0[7]);
  Ap[2] = make_float4(p0[8], p0[9], p0[10], p0[11]);
  Ap[3] = make_float4(p0[12], p0[13], p0[14], p0[15]);
  Ap[4] = make_float4(p1[0], p1[1], p1[2], p1[3]);
  Ap[5] = make_float4(p1[4], p1[5], p1[6], p1[7]);
  Ap[6] = make_float4(p1[8], p1[9], p1[10], p1[11]);
  Ap[7] = make_float4(p1[12], p1[13], p1[14], p1[15]);
  const int lane = tid & 63;
#pragma unroll
  for (int k = 0; k < 16; ++k) {
    float v = p0[k] + p1[k];
#pragma unroll
    for (int off = 32; off; off >>= 1) v += __shfl_xor(v, off);
    if (lane == 0) atomicAdd(&S0[b * 16 + k], v);
  }
}

// ---------------- Phase 4: agg[b,k,d] = sum_n A[b,n,k]*X[b,n,d]  (4 tokens/thread)
__global__ __launch_bounds__(256) void aggregate(const unsigned short* __restrict__ y,
    const float* __restrict__ bn_acc, const float* __restrict__ bn_g,
    const float* __restrict__ bn_b, const float* __restrict__ A,
    float* __restrict__ e_raw) {
  const int b = blockIdx.y;
  const int d0 = blockIdx.x * 4;
  const int tid = threadIdx.x;
  __shared__ float scsh[8];
  if (tid < 4) {
    int d = d0 + tid;
    float mu = bn_acc[d] * (1.f / 65536.f);
    float var = bn_acc[128 + d] * (1.f / 65536.f) - mu * mu;
    float sc = rsqrtf(var + 1e-5f) * bn_g[d];
    scsh[tid] = sc;
    scsh[4 + tid] = bn_b[d] - mu * sc;
  }
  __syncthreads();
  float sc[4], sh[4];
#pragma unroll
  for (int i = 0; i < 4; ++i) { sc[i] = scsh[i]; sh[i] = scsh[4 + i]; }
  float acc[4][16];
#pragma unroll
  for (int i = 0; i < 4; ++i)
#pragma unroll
    for (int k = 0; k < 16; ++k) acc[i][k] = 0.f;
  const unsigned short* yb = y + ((size_t)b * 128 + d0) * 4096;
  const float* Ab = A + (size_t)b * 65536;
  for (int it = 0; it < 4; ++it) {
    int n = (it * 256 + tid) * 4;
    float xv[4][4];   // [token][d-idx]
#pragma unroll
    for (int i = 0; i < 4; ++i) {
      uint2 pr = *(const uint2*)(yb + (size_t)i * 4096 + n);
      xv[0][i] = fmaxf(fmaf(bf2f(pr.x & 0xFFFFu), sc[i], sh[i]), 0.f);
      xv[1][i] = fmaxf(fmaf(bf2f(pr.x >> 16), sc[i], sh[i]), 0.f);
      xv[2][i] = fmaxf(fmaf(bf2f(pr.y & 0xFFFFu), sc[i], sh[i]), 0.f);
      xv[3][i] = fmaxf(fmaf(bf2f(pr.y >> 16), sc[i], sh[i]), 0.f);
    }
    const float4* ap = (const float4*)(Ab + (size_t)n * 16);
#pragma unroll
    for (int t = 0; t < 4; ++t) {
      float4 a0 = ap[t * 4 + 0], a1 = ap[t * 4 + 1];
      float4 a2 = ap[t * 4 + 2], a3 = ap[t * 4 + 3];
      float av[16] = {a0.x, a0.y, a0.z, a0.w, a1.x, a1.y, a1.z, a1.w,
                      a2.x, a2.y, a2.z, a2.w, a3.x, a3.y, a3.z, a3.w};
#pragma unroll
      for (int i = 0; i < 4; ++i)
#pragma unroll
        for (int k = 0; k < 16; ++k)
          acc[i][k] = fmaf(av[k], xv[t][i], acc[i][k]);
    }
  }
  const int lane = tid & 63, wid = tid >> 6;
  __shared__ float red[4][4][16];
#pragma unroll
  for (int i = 0; i < 4; ++i)
#pragma unroll
    for (int k = 0; k < 16; ++k) {
      float v = acc[i][k];
#pragma unroll
      for (int off = 32; off; off >>= 1) v += __shfl_xor(v, off);
      if (lane == 0) red[wid][i][k] = v;
    }
  __syncthreads();
  if (tid < 64) {
    int i = tid >> 4, k = tid & 15;
    float v = red[0][i][k] + red[1][i][k] + red[2][i][k] + red[3][i][k];
    e_raw[(size_t)b * 2048 + k * 128 + d0 + i] = v;
  }
}

// ---------------- Phase 5: gate = sigmoid((lin_w·e)/max(||e||,eps) + lin_b); e = agg - S0*cw
__global__ __launch_bounds__(256) void gate_kernel(const float* __restrict__ e_raw,
    const float* __restrict__ S0, const float* __restrict__ cw,
    const float* __restrict__ lin_w, const float* __restrict__ lin_b,
    float* __restrict__ gate) {
  const int b = blockIdx.y;
  const int c0 = blockIdx.x * 64;
  const int tid = threadIdx.x;
  __shared__ float es[2048];
  __shared__ float sred[256];
  __shared__ float s_inv;
  const float* eb = e_raw + (size_t)b * 2048;
  float ss = 0.f;
  for (int i = tid; i < 512; i += 256) {
    float4 v = ((const float4*)eb)[i];
    int k = i >> 5;
    int dbase = (i * 4) & 127;
    float s0k = S0[b * 16 + k];
    const float4 cv = *(const float4*)(cw + k * 128 + dbase);
    v.x -= s0k * cv.x; v.y -= s0k * cv.y; v.z -= s0k * cv.z; v.w -= s0k * cv.w;
    *(float4*)&es[i * 4] = v;
    ss += v.x * v.x + v.y * v.y + v.z * v.z + v.w * v.w;
  }
  sred[tid] = ss;
  __syncthreads();
  for (int off = 128; off; off >>= 1) {
    if (tid < off) sred[tid] += sred[tid + off];
    __syncthreads();
  }
  if (tid == 0) s_inv = 1.f / fmaxf(sqrtf(sred[0]), 1e-12f);
  __syncthreads();
  const int lane = tid & 63, wid = tid >> 6;
  for (int i = 0; i < 16; ++i) {
    int c = c0 + wid * 16 + i;
    const float* wr = lin_w + (size_t)c * 2048;
    float dotv = 0.f;
#pragma unroll
    for (int j = 0; j < 8; ++j) {
      int idx = j * 64 + lane;
      float4 wv = ((const float4*)wr)[idx];
      const float* ep = &es[idx * 4];
      dotv += wv.x * ep[0] + wv.y * ep[1] + wv.z * ep[2] + wv.w * ep[3];
    }
#pragma unroll
    for (int off = 32; off; off >>= 1) dotv += __shfl_xor(dotv, off);
    if (lane == 0) {
      float z = dotv * s_inv + lin_b[c];
      gate[b * 512 + c] = 1.f / (1.f + __expf(-z));
    }
  }
}

// ---------------- Phase 6: out = x * gate[b,c]
__global__ __launch_bounds__(256) void scale_kernel(const float* __restrict__ x,
    const float* __restrict__ gate, float* __restrict__ out, long n4) {
  long i = (long)blockIdx.x * blockDim.x + threadIdx.x;
  long stride = (long)gridDim.x * blockDim.x;
  for (; i < n4; i += stride) {
    float4 v = ((const float4*)x)[i];
    int c = (int)((i >> 10) & 511);
    int b = (int)(i >> 19);
    float g = gate[(b << 9) | c];
    v.x *= g; v.y *= g; v.z *= g; v.w *= g;
    ((float4*)out)[i] = v;
  }
}

extern "C" void kernel_launch(void* const* d_in, const int* in_sizes, int n_in,
                              void* d_out, int out_size, void* d_ws, size_t ws_size,
                              hipStream_t stream) {
  const float* x      = (const float*)d_in[0];
  const float* conv_w = (const float*)d_in[1];
  const float* conv_b = (const float*)d_in[2];
  const float* bn_g   = (const float*)d_in[3];
  const float* bn_b   = (const float*)d_in[4];
  const float* cw     = (const float*)d_in[5];
  const float* scale  = (const float*)d_in[6];
  const float* lin_w  = (const float*)d_in[7];
  const float* lin_b  = (const float*)d_in[8];
  float* out = (float*)d_out;
  float* ws  = (float*)d_ws;

  unsigned short* y = (unsigned short*)ws;          // [0, 4194304) floats
  float* A      = ws + 4194304;                     // 1,048,576
  float* S0     = ws + 5242880;                     // 256 (S0 | bn_acc contiguous)
  float* bn_acc = ws + 5243136;                     // 256
  float* e_raw  = ws + 5243392;                     // 32,768
  float* gate   = ws + 5276160;                     // 8,192
  unsigned short* w_bf = (unsigned short*)(ws + 5284352);   // 65,536 ushorts

  prep<<<64, 256, 0, stream>>>(conv_w, w_bf, S0);
  conv_mfma<<<dim3(32, 16), 256, 0, stream>>>(x, w_bf, conv_b, y, bn_acc);
  assign_softmax<<<dim3(8, 16), 256, 0, stream>>>(y, bn_acc, bn_g, bn_b, cw, scale, A, S0);
  aggregate<<<dim3(32, 16), 256, 0, stream>>>(y, bn_acc, bn_g, bn_b, A, e_raw);
  gate_kernel<<<dim3(8, 16), 256, 0, stream>>>(e_raw, S0, cw, lin_w, lin_b, gate);
  scale_kernel<<<4096, 256, 0, stream>>>(x, gate, out, 8388608L);
}

// Round 6
// 199.580 us; speedup vs baseline: 1.1245x; 1.0431x over previous
//
#include <hip/hip_runtime.h>
#include <hip/hip_bf16.h>

typedef __attribute__((ext_vector_type(8))) short short8;
typedef __attribute__((ext_vector_type(4))) float f32x4;

#define LDW 40   // conv LDS row pitch in ushorts (80 B)

__device__ __forceinline__ unsigned short f2bf(float f) {
  __hip_bfloat16 h = __float2bfloat16(f);
  return *(unsigned short*)&h;
}
__device__ __forceinline__ float bf2f(unsigned h) {
  return __uint_as_float(h << 16);
}
__device__ __forceinline__ unsigned pk2(float a, float b) {
  return (unsigned)f2bf(a) | ((unsigned)f2bf(b) << 16);
}
__device__ __forceinline__ unsigned long long pack4(float a, float b, float c, float d) {
  return (unsigned long long)pk2(a, b) | ((unsigned long long)pk2(c, d) << 32);
}

// ---------------- prep: w -> bf16, zero S0+bn_acc+e_acc
__global__ __launch_bounds__(256) void prep(const float* __restrict__ w,
    unsigned short* __restrict__ w_bf, float* __restrict__ S0, float* __restrict__ e_acc) {
  int i = blockIdx.x * 256 + threadIdx.x;        // 16384 threads
  float4 v = ((const float4*)w)[i];
  *(unsigned long long*)(w_bf + 4 * i) = pack4(v.x, v.y, v.z, v.w);
  e_acc[2 * i] = 0.f;
  e_acc[2 * i + 1] = 0.f;                        // 32768 floats
  if (blockIdx.x == 0) {
    S0[threadIdx.x] = 0.f;                       // S0[256]
    S0[256 + threadIdx.x] = 0.f;                 // bn_acc[256] (contiguous)
  }
}

// ---------------- Phase 1: conv as bf16 MFMA GEMM, y bf16 [b][d][n], BN partials via atomicAdd
__global__ __launch_bounds__(256) void conv_mfma(const float* __restrict__ x,
    const unsigned short* __restrict__ w_bf, const float* __restrict__ bias,
    unsigned short* __restrict__ y, float* __restrict__ bn_acc) {
  const int b = blockIdx.y;
  const int n0 = blockIdx.x * 128;
  const int tid = threadIdx.x;
  const int lane = tid & 63, wv = tid >> 6;
  const int li = lane & 15, q = lane >> 4;
  __shared__ unsigned short Wl[128 * LDW];
  __shared__ unsigned short Xl[128 * LDW];
  f32x4 acc[2][8];
#pragma unroll
  for (int m = 0; m < 2; ++m)
#pragma unroll
    for (int r = 0; r < 8; ++r) acc[m][r] = (f32x4){0.f, 0.f, 0.f, 0.f};
  const float* xb = x + (size_t)b * (512 * 4096) + n0;
  const int nq = tid & 31, cg = tid >> 5;
  for (int c0 = 0; c0 < 512; c0 += 32) {
#pragma unroll
    for (int i = 0; i < 2; ++i) {
      int idx = tid + i * 256;
      int d = idx >> 2, h = idx & 3;
      *(short8*)&Wl[d * LDW + h * 8] = *(const short8*)(w_bf + (size_t)d * 512 + c0 + h * 8);
    }
    {
      const float* xp = xb + (size_t)(c0 + cg * 4) * 4096 + nq * 4;
      float4 v0 = *(const float4*)(xp);
      float4 v1 = *(const float4*)(xp + 4096);
      float4 v2 = *(const float4*)(xp + 2 * 4096);
      float4 v3 = *(const float4*)(xp + 3 * 4096);
      const float* a0 = (const float*)&v0;
      const float* a1 = (const float*)&v1;
      const float* a2 = (const float*)&v2;
      const float* a3 = (const float*)&v3;
#pragma unroll
      for (int j = 0; j < 4; ++j) {
        *(unsigned long long*)&Xl[(nq * 4 + j) * LDW + cg * 4] =
            pack4(a0[j], a1[j], a2[j], a3[j]);
      }
    }
    __syncthreads();
    short8 af[2], bfr[8];
#pragma unroll
    for (int m = 0; m < 2; ++m)
      af[m] = *(const short8*)&Xl[(32 * wv + 16 * m + li) * LDW + q * 8];
#pragma unroll
    for (int r = 0; r < 8; ++r)
      bfr[r] = *(const short8*)&Wl[(16 * r + li) * LDW + q * 8];
#pragma unroll
    for (int m = 0; m < 2; ++m)
#pragma unroll
      for (int r = 0; r < 8; ++r)
        acc[m][r] = __builtin_amdgcn_mfma_f32_16x16x32_bf16(af[m], bfr[r], acc[m][r], 0, 0, 0);
    __syncthreads();
  }
  float s1[8], s2[8];
#pragma unroll
  for (int r = 0; r < 8; ++r) { s1[r] = 0.f; s2[r] = 0.f; }
#pragma unroll
  for (int r = 0; r < 8; ++r) {
    int d = 16 * r + li;
    float bb = bias[d];
#pragma unroll
    for (int m = 0; m < 2; ++m) {
      int nl = 32 * wv + 16 * m + 4 * q;
      float v0 = acc[m][r][0] + bb, v1 = acc[m][r][1] + bb;
      float v2 = acc[m][r][2] + bb, v3 = acc[m][r][3] + bb;
      s1[r] += v0 + v1 + v2 + v3;
      s2[r] += v0 * v0 + v1 * v1 + v2 * v2 + v3 * v3;
      *(unsigned long long*)(y + ((size_t)(b * 128 + d)) * 4096 + n0 + nl) =
          pack4(v0, v1, v2, v3);
    }
  }
#pragma unroll
  for (int r = 0; r < 8; ++r) {
    s1[r] += __shfl_xor(s1[r], 16); s1[r] += __shfl_xor(s1[r], 32);
    s2[r] += __shfl_xor(s2[r], 16); s2[r] += __shfl_xor(s2[r], 32);
  }
  float* red = (float*)Wl;
  if (lane < 16) {
#pragma unroll
    for (int r = 0; r < 8; ++r) {
      red[0 * 512 + wv * 128 + r * 16 + li] = s1[r];
      red[1 * 512 + wv * 128 + r * 16 + li] = s2[r];
    }
  }
  __syncthreads();
  {
    int s = tid >> 7, d = tid & 127;
    float v = red[s * 512 + d] + red[s * 512 + 128 + d]
            + red[s * 512 + 256 + d] + red[s * 512 + 384 + d];
    atomicAdd(&bn_acc[s * 128 + d], v);
  }
}

// ---------------- Phase 2 (fused assign+aggregate): per 128-token chunk:
// softmax assignment in VALU, E[k][d] += P^T X via MFMA, atomicAdd to e_acc.
__global__ __launch_bounds__(128) void encode(const unsigned short* __restrict__ y,
    const float* __restrict__ bn_acc, const float* __restrict__ bn_g,
    const float* __restrict__ bn_b, const float* __restrict__ cw,
    const float* __restrict__ scale, float* __restrict__ e_acc, float* __restrict__ S0) {
  const int b = blockIdx.y;
  const int n0 = blockIdx.x * 128;
  const int tid = threadIdx.x;          // 0..127
  const int lane = tid & 63, wv = tid >> 6;
  __shared__ unsigned short Xt[128 * 128];  // [d][tok] bf16, idx ^= (d&7)<<3
  __shared__ unsigned short Pt[16 * 128];   // [k][tok] bf16, idx ^= (k&7)<<3
  __shared__ float cws[16][128];
  __shared__ float c2s[16], scs[128], shs[128], sscale[16];
  for (int i = tid; i < 2048; i += 128) cws[i >> 7][i & 127] = cw[i];
  {
    float mu = bn_acc[tid] * (1.f / 65536.f);
    float var = bn_acc[128 + tid] * (1.f / 65536.f) - mu * mu;
    float sc = rsqrtf(var + 1e-5f) * bn_g[tid];
    scs[tid] = sc;
    shs[tid] = bn_b[tid] - mu * sc;
  }
  if (tid < 16) sscale[tid] = scale[tid];
  __syncthreads();
  if (tid < 16) {
    float s = 0.f;
#pragma unroll
    for (int d = 0; d < 128; ++d) s += cws[tid][d] * cws[tid][d];
    c2s[tid] = s;
  }
  __syncthreads();
  // P1: read y (2 tokens/thread), BN+ReLU, stage X^T to LDS, accumulate dots
  float dot0[16], dot1[16];
#pragma unroll
  for (int k = 0; k < 16; ++k) { dot0[k] = 0.f; dot1[k] = 0.f; }
  float x20 = 0.f, x21 = 0.f;
  const unsigned short* yb = y + (size_t)b * 524288 + n0 + 2 * tid;
  for (int d4 = 0; d4 < 128; d4 += 4) {
    float xv0[4], xv1[4];
#pragma unroll
    for (int j = 0; j < 4; ++j) {
      int d = d4 + j;
      unsigned pr = *(const unsigned*)(yb + (size_t)d * 4096);
      float sc = scs[d], sh = shs[d];
      float a0 = fmaxf(fmaf(bf2f(pr & 0xFFFFu), sc, sh), 0.f);
      float a1 = fmaxf(fmaf(bf2f(pr >> 16), sc, sh), 0.f);
      xv0[j] = a0; xv1[j] = a1;
      x20 = fmaf(a0, a0, x20); x21 = fmaf(a1, a1, x21);
      *(unsigned*)&Xt[(d * 128 + 2 * tid) ^ ((d & 7) << 3)] = pk2(a0, a1);
    }
#pragma unroll
    for (int k = 0; k < 16; ++k) {
      float4 cv = *(const float4*)&cws[k][d4];
      dot0[k] += xv0[0] * cv.x + xv0[1] * cv.y + xv0[2] * cv.z + xv0[3] * cv.w;
      dot1[k] += xv1[0] * cv.x + xv1[1] * cv.y + xv1[2] * cv.z + xv1[3] * cv.w;
    }
  }
  // softmax per token
  float p0[16], p1[16];
  {
    float m0 = -1e30f, m1 = -1e30f, sl0[16], sl1[16];
#pragma unroll
    for (int k = 0; k < 16; ++k) {
      sl0[k] = sscale[k] * (x20 + c2s[k] - 2.f * dot0[k]);
      sl1[k] = sscale[k] * (x21 + c2s[k] - 2.f * dot1[k]);
      m0 = fmaxf(m0, sl0[k]); m1 = fmaxf(m1, sl1[k]);
    }
    float s0 = 0.f, s1 = 0.f;
#pragma unroll
    for (int k = 0; k < 16; ++k) {
      p0[k] = __expf(sl0[k] - m0); s0 += p0[k];
      p1[k] = __expf(sl1[k] - m1); s1 += p1[k];
    }
    float i0 = 1.f / s0, i1 = 1.f / s1;
#pragma unroll
    for (int k = 0; k < 16; ++k) { p0[k] *= i0; p1[k] *= i1; }
  }
  // write P^T to LDS, reduce S0
#pragma unroll
  for (int k = 0; k < 16; ++k)
    *(unsigned*)&Pt[(k * 128 + 2 * tid) ^ ((k & 7) << 3)] = pk2(p0[k], p1[k]);
#pragma unroll
  for (int k = 0; k < 16; ++k) {
    float v = p0[k] + p1[k];
#pragma unroll
    for (int off = 32; off; off >>= 1) v += __shfl_xor(v, off);
    if (lane == 0) atomicAdd(&S0[b * 16 + k], v);
  }
  __syncthreads();
  // P3: E[k][d] = P^T (16x128tok) x X (128tok x 128d) via MFMA; wave wv owns 4 d-tiles
  const int li = lane & 15, q = lane >> 4;
  f32x4 eacc[4];
#pragma unroll
  for (int dt = 0; dt < 4; ++dt) eacc[dt] = (f32x4){0.f, 0.f, 0.f, 0.f};
#pragma unroll
  for (int ks = 0; ks < 4; ++ks) {
    int t0 = ks * 32 + q * 8;
    short8 af = *(const short8*)&Pt[(li * 128 + t0) ^ ((li & 7) << 3)];
#pragma unroll
    for (int dt = 0; dt < 4; ++dt) {
      int d = (wv * 4 + dt) * 16 + li;
      short8 bf = *(const short8*)&Xt[(d * 128 + t0) ^ ((d & 7) << 3)];
      eacc[dt] = __builtin_amdgcn_mfma_f32_16x16x32_bf16(af, bf, eacc[dt], 0, 0, 0);
    }
  }
  float* eb = e_acc + (size_t)b * 2048;
#pragma unroll
  for (int dt = 0; dt < 4; ++dt) {
    int d = (wv * 4 + dt) * 16 + li;
#pragma unroll
    for (int r = 0; r < 4; ++r) {
      int k = q * 4 + r;
      atomicAdd(&eb[k * 128 + d], eacc[dt][r]);
    }
  }
}

// ---------------- Phase 5: gate = sigmoid((lin_w·e)/max(||e||,eps) + lin_b); e = agg - S0*cw
__global__ __launch_bounds__(256) void gate_kernel(const float* __restrict__ e_raw,
    const float* __restrict__ S0, const float* __restrict__ cw,
    const float* __restrict__ lin_w, const float* __restrict__ lin_b,
    float* __restrict__ gate) {
  const int b = blockIdx.y;
  const int c0 = blockIdx.x * 64;
  const int tid = threadIdx.x;
  __shared__ float es[2048];
  __shared__ float sred[256];
  __shared__ float s_inv;
  const float* eb = e_raw + (size_t)b * 2048;
  float ss = 0.f;
  for (int i = tid; i < 512; i += 256) {
    float4 v = ((const float4*)eb)[i];
    int k = i >> 5;
    int dbase = (i * 4) & 127;
    float s0k = S0[b * 16 + k];
    const float4 cv = *(const float4*)(cw + k * 128 + dbase);
    v.x -= s0k * cv.x; v.y -= s0k * cv.y; v.z -= s0k * cv.z; v.w -= s0k * cv.w;
    *(float4*)&es[i * 4] = v;
    ss += v.x * v.x + v.y * v.y + v.z * v.z + v.w * v.w;
  }
  sred[tid] = ss;
  __syncthreads();
  for (int off = 128; off; off >>= 1) {
    if (tid < off) sred[tid] += sred[tid + off];
    __syncthreads();
  }
  if (tid == 0) s_inv = 1.f / fmaxf(sqrtf(sred[0]), 1e-12f);
  __syncthreads();
  const int lane = tid & 63, wid = tid >> 6;
  for (int i = 0; i < 16; ++i) {
    int c = c0 + wid * 16 + i;
    const float* wr = lin_w + (size_t)c * 2048;
    float dotv = 0.f;
#pragma unroll
    for (int j = 0; j < 8; ++j) {
      int idx = j * 64 + lane;
      float4 wv = ((const float4*)wr)[idx];
      const float* ep = &es[idx * 4];
      dotv += wv.x * ep[0] + wv.y * ep[1] + wv.z * ep[2] + wv.w * ep[3];
    }
#pragma unroll
    for (int off = 32; off; off >>= 1) dotv += __shfl_xor(dotv, off);
    if (lane == 0) {
      float z = dotv * s_inv + lin_b[c];
      gate[b * 512 + c] = 1.f / (1.f + __expf(-z));
    }
  }
}

// ---------------- Phase 6: out = x * gate[b,c]
__global__ __launch_bounds__(256) void scale_kernel(const float* __restrict__ x,
    const float* __restrict__ gate, float* __restrict__ out, long n4) {
  long i = (long)blockIdx.x * blockDim.x + threadIdx.x;
  long stride = (long)gridDim.x * blockDim.x;
  for (; i < n4; i += stride) {
    float4 v = ((const float4*)x)[i];
    int c = (int)((i >> 10) & 511);
    int b = (int)(i >> 19);
    float g = gate[(b << 9) | c];
    v.x *= g; v.y *= g; v.z *= g; v.w *= g;
    ((float4*)out)[i] = v;
  }
}

extern "C" void kernel_launch(void* const* d_in, const int* in_sizes, int n_in,
                              void* d_out, int out_size, void* d_ws, size_t ws_size,
                              hipStream_t stream) {
  const float* x      = (const float*)d_in[0];
  const float* conv_w = (const float*)d_in[1];
  const float* conv_b = (const float*)d_in[2];
  const float* bn_g   = (const float*)d_in[3];
  const float* bn_b   = (const float*)d_in[4];
  const float* cw     = (const float*)d_in[5];
  const float* scale  = (const float*)d_in[6];
  const float* lin_w  = (const float*)d_in[7];
  const float* lin_b  = (const float*)d_in[8];
  float* out = (float*)d_out;
  float* ws  = (float*)d_ws;

  unsigned short* y = (unsigned short*)ws;            // [0, 4194304) floats
  float* S0     = ws + 4194304;                       // 256 (S0 | bn_acc contiguous)
  float* bn_acc = ws + 4194560;                       // 256
  float* e_acc  = ws + 4194816;                       // 32768
  float* gate   = ws + 4227584;                       // 8192
  unsigned short* w_bf = (unsigned short*)(ws + 4235776);   // 65536 ushorts

  prep<<<64, 256, 0, stream>>>(conv_w, w_bf, S0, e_acc);
  conv_mfma<<<dim3(32, 16), 256, 0, stream>>>(x, w_bf, conv_b, y, bn_acc);
  encode<<<dim3(32, 16), 128, 0, stream>>>(y, bn_acc, bn_g, bn_b, cw, scale, e_acc, S0);
  gate_kernel<<<dim3(8, 16), 256, 0, stream>>>(e_acc, S0, cw, lin_w, lin_b, gate);
  scale_kernel<<<4096, 256, 0, stream>>>(x, gate, out, 8388608L);
}

// Round 8
// 156.841 us; speedup vs baseline: 1.4309x; 1.2725x over previous
//
#include <hip/hip_runtime.h>
#include <hip/hip_bf16.h>

typedef __attribute__((ext_vector_type(8))) short short8;
typedef __attribute__((ext_vector_type(4))) float f32x4;

#define LDW 40   // conv LDS row pitch in ushorts (80 B)

__device__ __forceinline__ unsigned short f2bf(float f) {
  __hip_bfloat16 h = __float2bfloat16(f);
  return *(unsigned short*)&h;
}
__device__ __forceinline__ float bf2f(unsigned h) {
  return __uint_as_float(h << 16);
}
__device__ __forceinline__ unsigned pk2(float a, float b) {
  return (unsigned)f2bf(a) | ((unsigned)f2bf(b) << 16);
}
__device__ __forceinline__ unsigned long long pack4(float a, float b, float c, float d) {
  return (unsigned long long)pk2(a, b) | ((unsigned long long)pk2(c, d) << 32);
}

// ---------------- prep: w -> bf16, zero S0+bn_acc+e_acc
__global__ __launch_bounds__(256) void prep(const float* __restrict__ w,
    unsigned short* __restrict__ w_bf, float* __restrict__ S0, float* __restrict__ e_acc) {
  int i = blockIdx.x * 256 + threadIdx.x;
  float4 v = ((const float4*)w)[i];
  *(unsigned long long*)(w_bf + 4 * i) = pack4(v.x, v.y, v.z, v.w);
  e_acc[2 * i] = 0.f;
  e_acc[2 * i + 1] = 0.f;
  if (blockIdx.x == 0) {
    S0[threadIdx.x] = 0.f;
    S0[256 + threadIdx.x] = 0.f;
  }
}

// ---------------- Phase 1: conv as bf16 MFMA GEMM, y bf16 [b][d][n], BN partials via atomicAdd
__global__ __launch_bounds__(256) void conv_mfma(const float* __restrict__ x,
    const unsigned short* __restrict__ w_bf, const float* __restrict__ bias,
    unsigned short* __restrict__ y, float* __restrict__ bn_acc) {
  const int b = blockIdx.y;
  const int n0 = blockIdx.x * 128;
  const int tid = threadIdx.x;
  const int lane = tid & 63, wv = tid >> 6;
  const int li = lane & 15, q = lane >> 4;
  __shared__ unsigned short Wl[128 * LDW];
  __shared__ unsigned short Xl[128 * LDW];
  f32x4 acc[2][8];
#pragma unroll
  for (int m = 0; m < 2; ++m)
#pragma unroll
    for (int r = 0; r < 8; ++r) acc[m][r] = (f32x4){0.f, 0.f, 0.f, 0.f};
  const float* xb = x + (size_t)b * (512 * 4096) + n0;
  const int nq = tid & 31, cg = tid >> 5;
  for (int c0 = 0; c0 < 512; c0 += 32) {
#pragma unroll
    for (int i = 0; i < 2; ++i) {
      int idx = tid + i * 256;
      int d = idx >> 2, h = idx & 3;
      *(short8*)&Wl[d * LDW + h * 8] = *(const short8*)(w_bf + (size_t)d * 512 + c0 + h * 8);
    }
    {
      const float* xp = xb + (size_t)(c0 + cg * 4) * 4096 + nq * 4;
      float4 v0 = *(const float4*)(xp);
      float4 v1 = *(const float4*)(xp + 4096);
      float4 v2 = *(const float4*)(xp + 2 * 4096);
      float4 v3 = *(const float4*)(xp + 3 * 4096);
      const float* a0 = (const float*)&v0;
      const float* a1 = (const float*)&v1;
      const float* a2 = (const float*)&v2;
      const float* a3 = (const float*)&v3;
#pragma unroll
      for (int j = 0; j < 4; ++j) {
        *(unsigned long long*)&Xl[(nq * 4 + j) * LDW + cg * 4] =
            pack4(a0[j], a1[j], a2[j], a3[j]);
      }
    }
    __syncthreads();
    short8 af[2], bfr[8];
#pragma unroll
    for (int m = 0; m < 2; ++m)
      af[m] = *(const short8*)&Xl[(32 * wv + 16 * m + li) * LDW + q * 8];
#pragma unroll
    for (int r = 0; r < 8; ++r)
      bfr[r] = *(const short8*)&Wl[(16 * r + li) * LDW + q * 8];
#pragma unroll
    for (int m = 0; m < 2; ++m)
#pragma unroll
      for (int r = 0; r < 8; ++r)
        acc[m][r] = __builtin_amdgcn_mfma_f32_16x16x32_bf16(af[m], bfr[r], acc[m][r], 0, 0, 0);
    __syncthreads();
  }
  float s1[8], s2[8];
#pragma unroll
  for (int r = 0; r < 8; ++r) { s1[r] = 0.f; s2[r] = 0.f; }
#pragma unroll
  for (int r = 0; r < 8; ++r) {
    int d = 16 * r + li;
    float bb = bias[d];
#pragma unroll
    for (int m = 0; m < 2; ++m) {
      int nl = 32 * wv + 16 * m + 4 * q;
      float v0 = acc[m][r][0] + bb, v1 = acc[m][r][1] + bb;
      float v2 = acc[m][r][2] + bb, v3 = acc[m][r][3] + bb;
      s1[r] += v0 + v1 + v2 + v3;
      s2[r] += v0 * v0 + v1 * v1 + v2 * v2 + v3 * v3;
      *(unsigned long long*)(y + ((size_t)(b * 128 + d)) * 4096 + n0 + nl) =
          pack4(v0, v1, v2, v3);
    }
  }
#pragma unroll
  for (int r = 0; r < 8; ++r) {
    s1[r] += __shfl_xor(s1[r], 16); s1[r] += __shfl_xor(s1[r], 32);
    s2[r] += __shfl_xor(s2[r], 16); s2[r] += __shfl_xor(s2[r], 32);
  }
  float* red = (float*)Wl;
  if (lane < 16) {
#pragma unroll
    for (int r = 0; r < 8; ++r) {
      red[0 * 512 + wv * 128 + r * 16 + li] = s1[r];
      red[1 * 512 + wv * 128 + r * 16 + li] = s2[r];
    }
  }
  __syncthreads();
  {
    int s = tid >> 7, d = tid & 127;
    float v = red[s * 512 + d] + red[s * 512 + 128 + d]
            + red[s * 512 + 256 + d] + red[s * 512 + 384 + d];
    atomicAdd(&bn_acc[s * 128 + d], v);
  }
}

// ---------------- Phase 2 (fused assign+aggregate): per 128-token chunk:
// softmax assignment in VALU, E[k][d] += P^T X via MFMA, atomicAdd to e_acc.
__global__ __launch_bounds__(128) void encode(const unsigned short* __restrict__ y,
    const float* __restrict__ bn_acc, const float* __restrict__ bn_g,
    const float* __restrict__ bn_b, const float* __restrict__ cw,
    const float* __restrict__ scale, float* __restrict__ e_acc, float* __restrict__ S0) {
  const int b = blockIdx.y;
  const int n0 = blockIdx.x * 128;
  const int tid = threadIdx.x;          // 0..127
  const int lane = tid & 63, wv = tid >> 6;
  __shared__ unsigned short Xt[128 * 128];  // [d][tok] bf16, idx ^= (d&7)<<3
  __shared__ unsigned short Pt[16 * 128];   // [k][tok] bf16, idx ^= (k&7)<<3
  __shared__ float cws[16][128];
  __shared__ float c2s[16], scs[128], shs[128], sscale[16];
  for (int i = tid; i < 2048; i += 128) cws[i >> 7][i & 127] = cw[i];
  {
    float mu = bn_acc[tid] * (1.f / 65536.f);
    float var = bn_acc[128 + tid] * (1.f / 65536.f) - mu * mu;
    float sc = rsqrtf(var + 1e-5f) * bn_g[tid];
    scs[tid] = sc;
    shs[tid] = bn_b[tid] - mu * sc;
  }
  if (tid < 16) sscale[tid] = scale[tid];
  __syncthreads();
  if (tid < 16) {
    float s = 0.f;
#pragma unroll
    for (int d = 0; d < 128; ++d) s += cws[tid][d] * cws[tid][d];
    c2s[tid] = s;
  }
  __syncthreads();
  float dot0[16], dot1[16];
#pragma unroll
  for (int k = 0; k < 16; ++k) { dot0[k] = 0.f; dot1[k] = 0.f; }
  float x20 = 0.f, x21 = 0.f;
  const unsigned short* yb = y + (size_t)b * 524288 + n0 + 2 * tid;
  for (int d4 = 0; d4 < 128; d4 += 4) {
    float xv0[4], xv1[4];
#pragma unroll
    for (int j = 0; j < 4; ++j) {
      int d = d4 + j;
      unsigned pr = *(const unsigned*)(yb + (size_t)d * 4096);
      float sc = scs[d], sh = shs[d];
      float a0 = fmaxf(fmaf(bf2f(pr & 0xFFFFu), sc, sh), 0.f);
      float a1 = fmaxf(fmaf(bf2f(pr >> 16), sc, sh), 0.f);
      xv0[j] = a0; xv1[j] = a1;
      x20 = fmaf(a0, a0, x20); x21 = fmaf(a1, a1, x21);
      *(unsigned*)&Xt[(d * 128 + 2 * tid) ^ ((d & 7) << 3)] = pk2(a0, a1);
    }
#pragma unroll
    for (int k = 0; k < 16; ++k) {
      float4 cv = *(const float4*)&cws[k][d4];
      dot0[k] += xv0[0] * cv.x + xv0[1] * cv.y + xv0[2] * cv.z + xv0[3] * cv.w;
      dot1[k] += xv1[0] * cv.x + xv1[1] * cv.y + xv1[2] * cv.z + xv1[3] * cv.w;
    }
  }
  float p0[16], p1[16];
  {
    float m0 = -1e30f, m1 = -1e30f, sl0[16], sl1[16];
#pragma unroll
    for (int k = 0; k < 16; ++k) {
      sl0[k] = sscale[k] * (x20 + c2s[k] - 2.f * dot0[k]);
      sl1[k] = sscale[k] * (x21 + c2s[k] - 2.f * dot1[k]);
      m0 = fmaxf(m0, sl0[k]); m1 = fmaxf(m1, sl1[k]);
    }
    float s0 = 0.f, s1 = 0.f;
#pragma unroll
    for (int k = 0; k < 16; ++k) {
      p0[k] = __expf(sl0[k] - m0); s0 += p0[k];
      p1[k] = __expf(sl1[k] - m1); s1 += p1[k];
    }
    float i0 = 1.f / s0, i1 = 1.f / s1;
#pragma unroll
    for (int k = 0; k < 16; ++k) { p0[k] *= i0; p1[k] *= i1; }
  }
#pragma unroll
  for (int k = 0; k < 16; ++k)
    *(unsigned*)&Pt[(k * 128 + 2 * tid) ^ ((k & 7) << 3)] = pk2(p0[k], p1[k]);
#pragma unroll
  for (int k = 0; k < 16; ++k) {
    float v = p0[k] + p1[k];
#pragma unroll
    for (int off = 32; off; off >>= 1) v += __shfl_xor(v, off);
    if (lane == 0) atomicAdd(&S0[b * 16 + k], v);
  }
  __syncthreads();
  const int li = lane & 15, q = lane >> 4;
  f32x4 eacc[4];
#pragma unroll
  for (int dt = 0; dt < 4; ++dt) eacc[dt] = (f32x4){0.f, 0.f, 0.f, 0.f};
#pragma unroll
  for (int ks = 0; ks < 4; ++ks) {
    int t0 = ks * 32 + q * 8;
    short8 af = *(const short8*)&Pt[(li * 128 + t0) ^ ((li & 7) << 3)];
#pragma unroll
    for (int dt = 0; dt < 4; ++dt) {
      int d = (wv * 4 + dt) * 16 + li;
      short8 bf = *(const short8*)&Xt[(d * 128 + t0) ^ ((d & 7) << 3)];
      eacc[dt] = __builtin_amdgcn_mfma_f32_16x16x32_bf16(af, bf, eacc[dt], 0, 0, 0);
    }
  }
  float* eb = e_acc + (size_t)b * 2048;
#pragma unroll
  for (int dt = 0; dt < 4; ++dt) {
    int d = (wv * 4 + dt) * 16 + li;
#pragma unroll
    for (int r = 0; r < 4; ++r) {
      int k = q * 4 + r;
      atomicAdd(&eb[k * 128 + d], eacc[dt][r]);
    }
  }
}

// ---------------- Phase 3 (fused gate+scale): per (b, 16-channel) block:
// e = e_acc - S0*cw, ||e||, 16 gates in LDS, then out = x * gate.
__global__ __launch_bounds__(256) void gscale(const float* __restrict__ e_acc,
    const float* __restrict__ S0, const float* __restrict__ cw,
    const float* __restrict__ lin_w, const float* __restrict__ lin_b,
    const float* __restrict__ x, float* __restrict__ out) {
  const int b = blockIdx.y;
  const int cb = blockIdx.x;          // 32 blocks x 16 channels
  const int tid = threadIdx.x;
  __shared__ float es[2048];
  __shared__ float sred[256];
  __shared__ float s_inv;
  __shared__ float gs[16];
  const float* eb = e_acc + (size_t)b * 2048;
  float ss = 0.f;
  for (int i = tid; i < 512; i += 256) {
    float4 v = ((const float4*)eb)[i];
    int k = i >> 5;
    int dbase = (i * 4) & 127;
    float s0k = S0[b * 16 + k];
    const float4 cv = *(const float4*)(cw + k * 128 + dbase);
    v.x -= s0k * cv.x; v.y -= s0k * cv.y; v.z -= s0k * cv.z; v.w -= s0k * cv.w;
    *(float4*)&es[i * 4] = v;
    ss += v.x * v.x + v.y * v.y + v.z * v.z + v.w * v.w;
  }
  sred[tid] = ss;
  __syncthreads();
  for (int off = 128; off; off >>= 1) {
    if (tid < off) sred[tid] += sred[tid + off];
    __syncthreads();
  }
  if (tid == 0) s_inv = 1.f / fmaxf(sqrtf(sred[0]), 1e-12f);
  __syncthreads();
  const int lane = tid & 63, wid = tid >> 6;
#pragma unroll
  for (int i = 0; i < 4; ++i) {
    int ch = wid * 4 + i;
    int c = cb * 16 + ch;
    const float* wr = lin_w + (size_t)c * 2048;
    float dotv = 0.f;
#pragma unroll
    for (int j = 0; j < 8; ++j) {
      int idx = j * 64 + lane;
      float4 wv = ((const float4*)wr)[idx];
      const float* ep = &es[idx * 4];
      dotv += wv.x * ep[0] + wv.y * ep[1] + wv.z * ep[2] + wv.w * ep[3];
    }
#pragma unroll
    for (int off = 32; off; off >>= 1) dotv += __shfl_xor(dotv, off);
    if (lane == 0) {
      float z = dotv * s_inv + lin_b[c];
      gs[ch] = 1.f / (1.f + __expf(-z));
    }
  }
  __syncthreads();
  const float* xb = x + ((size_t)b * 512 + cb * 16) * 4096;
  float* ob = out + ((size_t)b * 512 + cb * 16) * 4096;
#pragma unroll 2
  for (int ch = 0; ch < 16; ++ch) {
    float g = gs[ch];
    const float4* xp = (const float4*)(xb + ch * 4096);
    float4* op = (float4*)(ob + ch * 4096);
    for (int i = tid; i < 1024; i += 256) {
      float4 v = xp[i];
      v.x *= g; v.y *= g; v.z *= g; v.w *= g;
      op[i] = v;
    }
  }
}

extern "C" void kernel_launch(void* const* d_in, const int* in_sizes, int n_in,
                              void* d_out, int out_size, void* d_ws, size_t ws_size,
                              hipStream_t stream) {
  const float* x      = (const float*)d_in[0];
  const float* conv_w = (const float*)d_in[1];
  const float* conv_b = (const float*)d_in[2];
  const float* bn_g   = (const float*)d_in[3];
  const float* bn_b   = (const float*)d_in[4];
  const float* cw     = (const float*)d_in[5];
  const float* scale  = (const float*)d_in[6];
  const float* lin_w  = (const float*)d_in[7];
  const float* lin_b  = (const float*)d_in[8];
  float* out = (float*)d_out;
  float* ws  = (float*)d_ws;

  unsigned short* y = (unsigned short*)ws;            // [0, 4194304) floats
  float* S0     = ws + 4194304;                       // 256 (S0 | bn_acc contiguous)
  float* bn_acc = ws + 4194560;                       // 256
  float* e_acc  = ws + 4194816;                       // 32768
  unsigned short* w_bf = (unsigned short*)(ws + 4227584);   // 65536 ushorts

  prep<<<64, 256, 0, stream>>>(conv_w, w_bf, S0, e_acc);
  conv_mfma<<<dim3(32, 16), 256, 0, stream>>>(x, w_bf, conv_b, y, bn_acc);
  encode<<<dim3(32, 16), 128, 0, stream>>>(y, bn_acc, bn_g, bn_b, cw, scale, e_acc, S0);
  gscale<<<dim3(32, 16), 256, 0, stream>>>(e_acc, S0, cw, lin_w, lin_b, x, out);
}